// Round 7
// baseline (452.891 us; speedup 1.0000x reference)
//
#include <hip/hip_runtime.h>
#include <hip/hip_bf16.h>
#include <stdint.h>

// KGTN round 7. Single change vs R6: K-loop uses counted-vmcnt two-barrier
// schedule (T4): bar_A -> STAGE(t+1) -> vmcnt(L) -> bar_B -> COMPUTE(t).
// Tile t+1's loads stay in flight across the whole compute of tile t instead
// of being drained at issue+epsilon. L = per-wave loads/tile (6 MFR=2, 8 MFR=4).
// Everything else identical to R6 (tiles, grids, fused sigmoid epilogue,
// 3-way split-K h GEMM, T1/T2/T5).

typedef __attribute__((ext_vector_type(8))) short bf16x8;
typedef __attribute__((ext_vector_type(4))) float f32x4;
typedef __attribute__((ext_vector_type(4))) ushort u16x4;

typedef __attribute__((address_space(3))) void lds_void;
typedef const __attribute__((address_space(1))) void gbl_void;

__device__ __forceinline__ ushort f2b(float v) {
    union { float f; uint32_t u; } c; c.f = v;
    uint32_t u = c.u + 0x7FFFu + ((c.u >> 16) & 1u);   // RNE; inputs finite
    return (ushort)(u >> 16);
}

// Tile: BM=MFR*32 x BN=128, BK=64. A row-major bf16, Bt=B^T row-major bf16.
// Grid: x=N/128, y=M/BM, z in {1,2,3} (per-z A/lda/B-col-offset/C-offset).
// EPI: 0 = fp32 C, 1 = bf16 C, 2 = fused sigmoid (zv / rn_bf, no C).
// Requires gridDim.x*gridDim.y % 8 == 0, K % 64 == 0, K/64 >= 2.
template <int MFR, int EPI>
__global__ __launch_bounds__(256) void gemm_t(
    const ushort* __restrict__ A0, const ushort* __restrict__ A1,
    const ushort* __restrict__ A2, const ushort* __restrict__ Bt,
    void* __restrict__ Cv, int K, long lda01, long lda2, long ldb, long ldc,
    long bKoff, long cOff, float* __restrict__ zvp, ushort* __restrict__ rnp,
    const float* __restrict__ nodesp)
{
    __shared__ ushort As[2 * MFR * 2048];   // 2 x BM x 64
    __shared__ ushort Bs[2 * 8192];         // 2 x 128 x 64
    const int tid  = threadIdx.x;
    const int lane = tid & 63;
    const int wave = tid >> 6;
    const int wr = (wave >> 1) * (MFR * 16);   // wave row band
    const int wc = (wave & 1) * 64;            // wave col band

    // T1: bijective XCD-chunked remap of linearized (y,x) id. nwg%8==0.
    const int gx  = gridDim.x;
    const int nwg = gx * gridDim.y;
    int bid = blockIdx.y * gx + blockIdx.x;
    bid = (bid & 7) * (nwg >> 3) + (bid >> 3);
    const long bm = (long)(bid / gx) * (MFR * 32);
    const long bn = (long)(bid % gx) * 128;
    const int z  = blockIdx.z;

    const ushort* A  = (z == 0) ? A0 : (z == 1) ? A1 : A2;
    const long lda   = (z == 2) ? lda2 : lda01;
    const ushort* Bp = Bt + (long)z * bKoff;

    const int l15  = lane & 15;
    const int kg   = lane >> 4;                    // 0..3
    const int srow = lane >> 3;                    // 0..7
    const int gsw  = ((lane & 7) ^ srow) & 7;      // pre-swizzled src granule

    f32x4 acc[MFR][4] = {};

    // stage one BK=64 K-tile (A: MFR slots/wave, B: 4 slots/wave)
    auto STAGE = [&](int k0, int buf) {
        #pragma unroll
        for (int p = 0; p < MFR; ++p) {
            const int slot = wave * MFR + p;       // BM/8 slots x 8 rows
            const int row  = slot * 8 + srow;
            const ushort* ga = A + (bm + row) * lda + (k0 + gsw * 8);
            __builtin_amdgcn_global_load_lds((gbl_void*)ga,
                (lds_void*)(As + buf * MFR * 2048 + slot * 512), 16, 0, 0);
        }
        #pragma unroll
        for (int p = 0; p < 4; ++p) {
            const int slot = wave * 4 + p;         // 16 slots x 8 rows = 128
            const int row  = slot * 8 + srow;
            const ushort* gb = Bp + (bn + row) * ldb + (k0 + gsw * 8);
            __builtin_amdgcn_global_load_lds((gbl_void*)gb,
                (lds_void*)(Bs + buf * 8192 + slot * 512), 16, 0, 0);
        }
    };

    auto COMPUTE = [&](int buf) {
        const ushort* as = As + buf * MFR * 2048;
        const ushort* bs = Bs + buf * 8192;
        #pragma unroll
        for (int kk = 0; kk < 2; ++kk) {
            const int ph = (((kk * 4 + kg) ^ (lane & 7)) & 7) * 8;
            bf16x8 af[MFR], bv[4];
            #pragma unroll
            for (int m = 0; m < MFR; ++m)
                af[m] = *(const bf16x8*)(as + (wr + m * 16 + l15) * 64 + ph);
            #pragma unroll
            for (int n = 0; n < 4; ++n)
                bv[n] = *(const bf16x8*)(bs + (wc + n * 16 + l15) * 64 + ph);
            __builtin_amdgcn_s_setprio(1);
            #pragma unroll
            for (int m = 0; m < MFR; ++m)
                #pragma unroll
                for (int n = 0; n < 4; ++n)
                    acc[m][n] = __builtin_amdgcn_mfma_f32_16x16x32_bf16(
                        af[m], bv[n], acc[m][n], 0, 0, 0);
            __builtin_amdgcn_s_setprio(0);
        }
    };

#define FENCE __builtin_amdgcn_sched_barrier(0)

    const int T = K >> 6;
    STAGE(0, 0);
    for (int t = 0; t < T; ++t) {
        FENCE;
        __builtin_amdgcn_s_barrier();          // bar_A: compute(t-1) done
        FENCE;
        if (t + 1 < T) {
            STAGE((t + 1) * 64, (t + 1) & 1);  // into buf of t-1 (safe)
            FENCE;
            if (MFR == 2) asm volatile("s_waitcnt vmcnt(6)" ::: "memory");
            else          asm volatile("s_waitcnt vmcnt(8)" ::: "memory");
        } else {
            asm volatile("s_waitcnt vmcnt(0)" ::: "memory");
        }
        FENCE;
        __builtin_amdgcn_s_barrier();          // bar_B: tile t visible
        FENCE;
        COMPUTE(t & 1);
    }
#undef FENCE

    // C/D layout: col = lane&15, row = (lane>>4)*4 + reg   [m89-verified]
    const int cr0 = (lane >> 4) * 4;
    const bool zhalf = (bn < 1024);        // EPI2 only
    #pragma unroll
    for (int m = 0; m < MFR; ++m) {
        #pragma unroll
        for (int j = 0; j < 4; ++j) {
            const long r = bm + wr + m * 16 + cr0 + j;
            #pragma unroll
            for (int n = 0; n < 4; ++n) {
                const long c = bn + wc + n * 16 + l15;
                if (EPI == 0) {
                    ((float*)Cv + cOff * z)[r * ldc + c] = acc[m][n][j];
                } else if (EPI == 1) {
                    ((ushort*)Cv + cOff * z)[r * ldc + c] = f2b(acc[m][n][j]);
                } else {
                    const float s = 1.f / (1.f + __expf(-acc[m][n][j]));
                    if (zhalf) zvp[r * 1024 + c] = s;
                    else {
                        const long cc = c - 1024;
                        rnp[r * 1024 + cc] = f2b(s * nodesp[r * 1024 + cc]);
                    }
                }
            }
        }
    }
}

// fp32 -> bf16 elementwise, 4 elems/thread. n4 = total/4.
__global__ __launch_bounds__(256) void cvt_bf16_k(const float* __restrict__ src,
                                                  ushort* __restrict__ dst, long n4) {
    long i = (long)blockIdx.x * 256 + threadIdx.x;
    if (i >= n4) return;
    f32x4 v = *(const f32x4*)(src + i * 4);
    u16x4 o;
    #pragma unroll
    for (int j = 0; j < 4; ++j) o[j] = f2b(v[j]);
    *(u16x4*)(dst + i * 4) = o;
}

// dst[c*dld + r] = bf16(src[r*C + c]). Grid (C/32, R/32), block 256.
__global__ __launch_bounds__(256) void transpose_cvt(const float* __restrict__ src,
                                                     ushort* __restrict__ dst,
                                                     int R, int C, int dld) {
    __shared__ float t[32][33];
    const int c0 = blockIdx.x * 32, r0 = blockIdx.y * 32;
    const int tx = threadIdx.x & 31, ty = threadIdx.x >> 5;
    #pragma unroll
    for (int i = 0; i < 32; i += 8)
        t[ty + i][tx] = src[(long)(r0 + ty + i) * C + c0 + tx];
    __syncthreads();
    #pragma unroll
    for (int i = 0; i < 32; i += 8)
        dst[(long)(c0 + ty + i) * dld + r0 + tx] = f2b(t[tx][ty + i]);
}

// From lfw [1024(h), 2048(N)]: nodesT_bf[h][N], nodes f32 [N][h],
// nodes_bf -> avn cols 2048:3072, init_bf -> ninit cols 1024:2048.
__global__ __launch_bounds__(256) void init_nodes_k(const float* __restrict__ lfw,
        ushort* __restrict__ nodesT, float* __restrict__ nodes,
        ushort* __restrict__ avn, ushort* __restrict__ ninit) {
    __shared__ float t[32][33];
    const int n0 = blockIdx.x * 32, h0 = blockIdx.y * 32;
    const int tx = threadIdx.x & 31, ty = threadIdx.x >> 5;
    #pragma unroll
    for (int i = 0; i < 32; i += 8) {
        float v = lfw[(long)(h0 + ty + i) * 2048 + n0 + tx];
        nodesT[(long)(h0 + ty + i) * 2048 + n0 + tx] = f2b(v);
        t[ty + i][tx] = v;
    }
    __syncthreads();
    #pragma unroll
    for (int i = 0; i < 32; i += 8) {
        const int n = n0 + ty + i, hh = h0 + tx;
        float v = t[tx][ty + i];
        nodes[(long)n * 1024 + hh] = v;
        ushort b = f2b(v);
        avn[(long)n * 3072 + 2048 + hh] = b;
        ninit[(long)n * 2048 + 1024 + hh] = b;
    }
}

// nodes = (1-z)*nodes + z*tanh(hp0+hp1+hp2); emit nodes_bf + transposed copy.
__global__ __launch_bounds__(256) void update_nodes_k(float* __restrict__ nodes,
        const float* __restrict__ zv, const float* __restrict__ hp,
        ushort* __restrict__ avn, ushort* __restrict__ ninit,
        ushort* __restrict__ nodesT) {
    __shared__ float t[32][33];
    const int c0 = blockIdx.x * 32, r0 = blockIdx.y * 32;
    const int tx = threadIdx.x & 31, ty = threadIdx.x >> 5;
    #pragma unroll
    for (int i = 0; i < 32; i += 8) {
        const int r = r0 + ty + i, c = c0 + tx;
        const long idx = (long)r * 1024 + c;
        const float z = zv[idx];
        const float hsum = hp[idx] + hp[idx + 2097152] + hp[idx + 4194304];
        const float nn = (1.f - z) * nodes[idx] + z * tanhf(hsum);
        nodes[idx] = nn;
        const ushort b = f2b(nn);
        avn[(long)r * 3072 + 2048 + c] = b;
        ninit[(long)r * 2048 + c] = b;
        t[ty + i][tx] = nn;
    }
    __syncthreads();
    #pragma unroll
    for (int i = 0; i < 32; i += 8)
        nodesT[(long)(c0 + ty + i) * 2048 + r0 + tx] = f2b(t[tx][ty + i]);
}

// v = sop0+sop1+bias; so_bf = bf16(v); partial sums of v^2. 1024 blocks.
__global__ __launch_bounds__(256) void bias_l2(const float* __restrict__ s,
        const float* __restrict__ bias, ushort* __restrict__ so_bf,
        float* __restrict__ partials) {
    __shared__ float red[256];
    const int tid = threadIdx.x;
    const long base = (long)blockIdx.x * 2048;
    float sum = 0.f;
    #pragma unroll
    for (int it = 0; it < 8; ++it) {
        const long i = base + tid + it * 256;
        const float v = s[i] + s[i + 2097152] + bias[i & 1023];
        so_bf[i] = f2b(v);
        sum += v * v;
    }
    red[tid] = sum;
    __syncthreads();
    #pragma unroll
    for (int w = 128; w > 0; w >>= 1) {
        if (tid < w) red[tid] += red[tid + w];
        __syncthreads();
    }
    if (tid == 0) partials[blockIdx.x] = red[0];
}

__global__ __launch_bounds__(256) void reduce_final(const float* __restrict__ partials,
                                                    float* __restrict__ out) {
    __shared__ float red[256];
    const int tid = threadIdx.x;
    red[tid] = partials[tid] + partials[tid + 256] + partials[tid + 512] + partials[tid + 768];
    __syncthreads();
    #pragma unroll
    for (int w = 128; w > 0; w >>= 1) {
        if (tid < w) red[tid] += red[tid + w];
        __syncthreads();
    }
    if (tid == 0) out[0] = red[0];
}

extern "C" void kernel_launch(void* const* d_in, const int* in_sizes, int n_in,
                              void* d_out, int out_size, void* d_ws, size_t ws_size,
                              hipStream_t stream) {
    const float* x   = (const float*)d_in[0];   // [8192,1024]
    const float* lfw = (const float*)d_in[1];   // [1024,2048]
    const float* inM = (const float*)d_in[2];   // [2048,2048]
    const float* w3w = (const float*)d_in[3];
    const float* w3u = (const float*)d_in[4];
    const float* w4w = (const float*)d_in[5];
    const float* w4u = (const float*)d_in[6];
    const float* w5w = (const float*)d_in[7];
    const float* w5u = (const float*)d_in[8];
    const float* fcw = (const float*)d_in[9];
    const float* fcb = (const float*)d_in[10];
    float* out = (float*)d_out;

    const int B = 8192, N = 2048;
    const long NH = 2097152;

    // d_out front as fp32 scratch (dead before final GEMM rewrites d_out):
    float* hpre = out;                  // 3x [2048,1024] (24MB)
    float* sop  = out + 6291456l;       // 2x [2048,1024] (16MB)

    char* p = (char*)d_ws;
    auto alloc = [&](size_t bytes) {
        char* r = p; p += (bytes + 255) & ~(size_t)255; return r;
    };
    float*  nodes    = (float*)alloc(NH * 4);
    float*  zv       = (float*)alloc(NH * 4);
    float*  partials = (float*)alloc(1024 * 4);
    ushort* avn      = (ushort*)alloc(6291456ull * 2);  // [2048,3072]
    ushort* rn_bf    = (ushort*)alloc(NH * 2);          // [2048,1024]
    ushort* nodesT   = (ushort*)alloc(NH * 2);          // [1024,2048]
    ushort* ninit    = (ushort*)alloc(4194304ull * 2);  // [2048,2048]
    ushort* inM_bf   = (ushort*)alloc(4194304ull * 2);
    ushort* inMT_bf  = (ushort*)alloc(4194304ull * 2);
    ushort* Wzr_t    = (ushort*)alloc(6291456ull * 2);  // [2048,3072]
    ushort* W5_t     = (ushort*)alloc(3145728ull * 2);  // [1024,3072]
    ushort* fcw_t    = (ushort*)alloc(NH * 2);          // [1024,2048]
    ushort* x_bf     = (ushort*)alloc(8388608ull * 2);  // [8192,1024]
    ushort* so_bf    = (ushort*)alloc(NH * 2);          // [2048,1024]

    const dim3 tb(256);

    // ---- prep ----
    cvt_bf16_k<<<8192, tb, 0, stream>>>(x, x_bf, 2097152);
    cvt_bf16_k<<<4096, tb, 0, stream>>>(inM, inM_bf, 1048576);
    transpose_cvt<<<dim3(64, 64), tb, 0, stream>>>(inM, inMT_bf, 2048, 2048, 2048);
    transpose_cvt<<<dim3(32, 64), tb, 0, stream>>>(w3w, Wzr_t,                    2048, 1024, 3072);
    transpose_cvt<<<dim3(32, 32), tb, 0, stream>>>(w3u, Wzr_t + 2048,             1024, 1024, 3072);
    transpose_cvt<<<dim3(32, 64), tb, 0, stream>>>(w4w, Wzr_t + 3145728l,         2048, 1024, 3072);
    transpose_cvt<<<dim3(32, 32), tb, 0, stream>>>(w4u, Wzr_t + 3145728l + 2048,  1024, 1024, 3072);
    transpose_cvt<<<dim3(32, 64), tb, 0, stream>>>(w5w, W5_t,                     2048, 1024, 3072);
    transpose_cvt<<<dim3(32, 32), tb, 0, stream>>>(w5u, W5_t + 2048,              1024, 1024, 3072);
    transpose_cvt<<<dim3(32, 64), tb, 0, stream>>>(fcw, fcw_t,                    2048, 1024, 2048);
    init_nodes_k<<<dim3(64, 32), tb, 0, stream>>>(lfw, nodesT, nodes, avn, ninit);

    // ---- GGNN time steps ----
    for (int t = 0; t < 3; ++t) {
        // avn[:,0:1024] = in@nodes ; avn[:,1024:2048] = inT@nodes (512 blocks)
        gemm_t<2, 1><<<dim3(8, 32, 2), tb, 0, stream>>>(
            inM_bf, inMT_bf, nullptr, nodesT, avn,
            2048, 2048, 0, 2048, 3072, 0, 1024, nullptr, nullptr, nullptr);
        // fused zr: zv = sigmoid(avn@[w3]), rn_bf = sigmoid(avn@[w4])*nodes
        gemm_t<2, 2><<<dim3(16, 32, 1), tb, 0, stream>>>(
            avn, nullptr, nullptr, Wzr_t, nullptr,
            3072, 3072, 0, 3072, 0, 0, 0, zv, rn_bf, nodes);
        // hpre(z) partials: z0 = avn[:,0:1024]@W5[0:1024], z1 = avn[:,1024:2048]
        //   @W5[1024:2048], z2 = rn_bf@W5[2048:3072]   (768 blocks, balanced)
        gemm_t<2, 0><<<dim3(8, 32, 3), tb, 0, stream>>>(
            avn, avn + 1024, rn_bf, W5_t, hpre,
            1024, 3072, 1024, 3072, 1024, 1024, 2097152, nullptr, nullptr, nullptr);
        update_nodes_k<<<dim3(32, 64), tb, 0, stream>>>(nodes, zv, hpre, avn, ninit, nodesT);
    }

    // step_out partials = [nodes|init] @ fc_out_w  (split-K x2, 512 blocks)
    gemm_t<2, 0><<<dim3(8, 32, 2), tb, 0, stream>>>(
        ninit, ninit + 1024, nullptr, fcw_t, sop,
        1024, 2048, 0, 2048, 1024, 1024, 2097152, nullptr, nullptr, nullptr);
    bias_l2<<<1024, tb, 0, stream>>>(sop, fcb, so_bf, partials);
    reduce_final<<<1, tb, 0, stream>>>(partials, out + (long)B * N);
    // output = x @ step_out^T  (128x128 tile, 1024 blocks, 2 blocks/CU)
    gemm_t<4, 0><<<dim3(16, 64, 1), tb, 0, stream>>>(
        x_bf, nullptr, nullptr, so_bf, out,
        1024, 1024, 0, 1024, 2048, 0, 0, nullptr, nullptr, nullptr);
}